// Round 12
// baseline (753.744 us; speedup 1.0000x reference)
//
#include <hip/hip_runtime.h>
#include <hip/hip_bf16.h>
#include <math.h>

#define NVERT 150000
#define NFACE 300000
#define LVOL  192
#define TVB   32

// mega_prep block-range partition
#define NB_NORM   1172                // (300000+255)/256
#define NB_POOL1  3456                // 884736/256
#define NB_POOL2  432                 // 110592/256
#define NB_PW     1024                // 262144/256
#define NB_PC     193                 // (49152+128+255)/256
#define POOL1_START (NB_NORM)
#define POOL2_START (NB_NORM + NB_POOL1)
#define PW_START    (NB_NORM + NB_POOL1 + NB_POOL2)
#define PC_START    (NB_NORM + NB_POOL1 + NB_POOL2 + NB_PW)
#define NB_MEGA     (NB_NORM + NB_POOL1 + NB_POOL2 + NB_PW + NB_PC)

// big-ws split-path layout threshold
#define XLOC_ROWS 150016
#define WS_BIG_NEED 44808576ull

typedef short v8s __attribute__((ext_vector_type(8)));
typedef float v4f __attribute__((ext_vector_type(4)));

__device__ __forceinline__ float s2f(short s) {
    unsigned int u = ((unsigned int)(unsigned short)s) << 16;
    return __builtin_bit_cast(float, u);
}
__device__ __forceinline__ short f2s(float f) {
    __hip_bfloat16 h = __float2bfloat16(f);
    return __builtin_bit_cast(short, h);
}
__device__ __forceinline__ float lrelu(float x) { return x > 0.f ? x : 0.15f * x; }

__device__ __forceinline__ float ldf(const void* __restrict__ p, int i, int bf) {
    return bf ? s2f(((const short*)p)[i]) : ((const float*)p)[i];
}

// ---- detect input dtype (bf16 vs fp32) ----
__global__ void detect_kernel(const void* __restrict__ v, int* __restrict__ flag) {
    __shared__ int s_ok;
    int t = threadIdx.x;
    if (t == 0) s_ok = 1;
    __syncthreads();
    float x = s2f(((const short*)v)[t]);
    if (!(fabsf(x) <= 1.0f)) atomicAnd(&s_ok, 0);
    __syncthreads();
    if (t == 0) *flag = s_ok;
}

// ---------------- mega prep: normals | pool1 | pool2-direct | transposes | Wcomb ----------------
__global__ __launch_bounds__(256) void mega_prep_kernel(
    const void* __restrict__ v, const int* __restrict__ f, float* __restrict__ n_accum,
    const void* __restrict__ volume,
    short* __restrict__ vol1b, float* __restrict__ vol1f,
    short* __restrict__ vol2b, float* __restrict__ vol2f,
    const void* __restrict__ fc2_w, const void* __restrict__ fc3_w,
    short* __restrict__ fc2T, short* __restrict__ fc3T,
    const void* __restrict__ conv_w, const void* __restrict__ lfc_w,
    const void* __restrict__ conv_b, const void* __restrict__ lfc_b,
    short* __restrict__ Wcomb, float* __restrict__ bcomb,
    const int* __restrict__ flag, int bigws)
{
    const int bf = *flag;
    const int bid = blockIdx.x;
    const int t = threadIdx.x;

    if (bid < NB_NORM) {
        int ft = bid * 256 + t;
        if (ft >= NFACE) return;
        int i0 = f[ft * 3 + 0], i1 = f[ft * 3 + 1], i2 = f[ft * 3 + 2];
        float p0x = ldf(v, i0 * 3 + 0, bf), p0y = ldf(v, i0 * 3 + 1, bf), p0z = ldf(v, i0 * 3 + 2, bf);
        float p1x = ldf(v, i1 * 3 + 0, bf), p1y = ldf(v, i1 * 3 + 1, bf), p1z = ldf(v, i1 * 3 + 2, bf);
        float p2x = ldf(v, i2 * 3 + 0, bf), p2y = ldf(v, i2 * 3 + 1, bf), p2z = ldf(v, i2 * 3 + 2, bf);
        float e1x = p1x - p0x, e1y = p1y - p0y, e1z = p1z - p0z;
        float e2x = p2x - p0x, e2y = p2y - p0y, e2z = p2z - p0z;
        float cx = e1y * e2z - e1z * e2y;
        float cy = e1z * e2x - e1x * e2z;
        float cz = e1x * e2y - e1y * e2x;
        atomicAdd(&n_accum[i0 * 3 + 0], cx); atomicAdd(&n_accum[i0 * 3 + 1], cy); atomicAdd(&n_accum[i0 * 3 + 2], cz);
        atomicAdd(&n_accum[i1 * 3 + 0], cx); atomicAdd(&n_accum[i1 * 3 + 1], cy); atomicAdd(&n_accum[i1 * 3 + 2], cz);
        atomicAdd(&n_accum[i2 * 3 + 0], cx); atomicAdd(&n_accum[i2 * 3 + 1], cy); atomicAdd(&n_accum[i2 * 3 + 2], cz);
    } else if (bid < POOL2_START) {
        int id = (bid - POOL1_START) * 256 + t;
        int z = id % 96, y = (id / 96) % 96, x = id / (96 * 96);
        float s = 0.f;
        #pragma unroll
        for (int a = 0; a < 2; a++)
            #pragma unroll
            for (int b = 0; b < 2; b++)
                #pragma unroll
                for (int c = 0; c < 2; c++)
                    s += ldf(volume, (2 * x + a) * (LVOL * LVOL) + (2 * y + b) * LVOL + (2 * z + c), bf);
        s *= 0.125f;
        if (bigws) vol1f[id] = s; else vol1b[id] = f2s(s);
    } else if (bid < PW_START) {
        int id = (bid - POOL2_START) * 256 + t;
        int z = id % 48, y = (id / 48) % 48, x = id / (48 * 48);
        float s = 0.f;
        for (int a = 0; a < 4; a++)
            for (int b = 0; b < 4; b++)
                #pragma unroll
                for (int c = 0; c < 4; c++)
                    s += ldf(volume, (4 * x + a) * (LVOL * LVOL) + (4 * y + b) * LVOL + (4 * z + c), bf);
        s *= 0.015625f;
        if (bigws) vol2f[id] = s; else vol2b[id] = f2s(s);
    } else if (bid < PC_START) {
        int id = (bid - PW_START) * 256 + t;
        if (id < 131072) {
            int j = id >> 8, k = id & 255;
            fc2T[id] = f2s(ldf(fc2_w, k * 512 + j, bf));
        } else {
            int i = id - 131072;
            int j = i >> 9, k = i & 511;
            fc3T[i] = f2s(ldf(fc3_w, k * 256 + j, bf));
        }
    } else {
        int id = (bid - PC_START) * 256 + t;
        if (id < 49152) {
            int j = id / 384, k = id - j * 384;
            float acc = 0.f;
            if (k < 375) {
                float a0 = 0.f, a1 = 0.f, a2 = 0.f, a3 = 0.f;
                for (int o = 0; o < 128; o += 4) {
                    a0 += ldf(conv_w, (o + 0) * 375 + k, bf) * ldf(lfc_w, (o + 0) * 128 + j, bf);
                    a1 += ldf(conv_w, (o + 1) * 375 + k, bf) * ldf(lfc_w, (o + 1) * 128 + j, bf);
                    a2 += ldf(conv_w, (o + 2) * 375 + k, bf) * ldf(lfc_w, (o + 2) * 128 + j, bf);
                    a3 += ldf(conv_w, (o + 3) * 375 + k, bf) * ldf(lfc_w, (o + 3) * 128 + j, bf);
                }
                acc = (a0 + a1) + (a2 + a3);
            }
            Wcomb[j * 384 + k] = f2s(acc);
        } else if (id < 49152 + 128) {
            int j = id - 49152;
            float acc = ldf(lfc_b, j, bf);
            for (int o = 0; o < 128; o++) acc += ldf(conv_b, o, bf) * ldf(lfc_w, o * 128 + j, bf);
            bcomb[j] = acc;
        }
    }
}

// ================= BIG-WS SPLIT PATH =================

// ---- kernel A: gather + conv GEMM -> xloc global ----
__global__ __launch_bounds__(256, 6) void gather_conv_kernel(
    const void* __restrict__ v,
    const void* __restrict__ volume,
    const float* __restrict__ vol1f,
    const float* __restrict__ vol2f,
    const short* __restrict__ Wcomb,
    const float* __restrict__ bcomb,
    short* __restrict__ xloc,
    const int* __restrict__ flag)
{
    __shared__ __align__(16) short sCube[TVB * 392];
    __shared__ int sIdx[TVB * 4];

    const int bf = *flag;
    const int t = threadIdx.x;
    const int base = blockIdx.x * TVB;
    const int w = t >> 6, L = t & 63, q = L >> 4, ln = L & 15;

    if (t < TVB) {
        int vert = min(base + t, NVERT - 1);
        float vx = ldf(v, vert * 3 + 0, bf);
        float vy = ldf(v, vert * 3 + 1, bf);
        float vz = ldf(v, vert * 3 + 2, bf);
        #pragma unroll
        for (int n = 0; n < 3; n++) {
            float scl = (n == 0) ? 96.0f : (n == 1 ? 48.0f : 24.0f);
            int dim = LVOL >> n, lim = dim - 3;
            int cx = min(max((int)rintf((vx + 1.0f) * scl), 2), lim);
            int cy = min(max((int)rintf((vy + 1.0f) * scl), 2), lim);
            int cz = min(max((int)rintf((vz + 1.0f) * scl), 2), lim);
            sIdx[t * 4 + n] = (cx * dim + cy) * dim + (cz - 2);
        }
    }
    __syncthreads();

    for (int idx = t; idx < TVB * 75; idx += 256) {
        int n   = idx / 800;
        int rem = idx - n * 800;
        int vl  = rem / 25;
        int dd  = rem - vl * 25;
        int di  = dd / 5, dj = dd - di * 5;
        int dim = LVOL >> n;
        int addr = sIdx[vl * 4 + n] + (di - 2) * dim * dim + (dj - 2) * dim;
        short* dst = &sCube[vl * 392 + n * 125 + dd * 5];
        if (n == 0) {
            if (bf) {
                const short* vp = (const short*)volume;
                #pragma unroll
                for (int i = 0; i < 5; i++) dst[i] = vp[addr + i];
            } else {
                const float* vp = (const float*)volume;
                #pragma unroll
                for (int i = 0; i < 5; i++) dst[i] = f2s(vp[addr + i]);
            }
        } else {
            const float* lvl = (n == 1) ? vol1f : vol2f;
            #pragma unroll
            for (int i = 0; i < 5; i++) dst[i] = f2s(lvl[addr + i]);
        }
    }
    for (int idx = t; idx < TVB * 9; idx += 256) {
        int vl = idx / 9, rr = idx - vl * 9;
        sCube[vl * 392 + 375 + rr] = 0;
    }
    __syncthreads();

    #pragma unroll
    for (int nt = 0; nt < 2; nt++) {
        int col = w * 32 + nt * 16 + ln;
        v4f acc0 = {0.f, 0.f, 0.f, 0.f}, acc1 = {0.f, 0.f, 0.f, 0.f};
        #pragma unroll
        for (int k0 = 0; k0 < 12; k0++) {
            v8s b  = *(const v8s*)&Wcomb[col * 384 + k0 * 32 + q * 8];
            v8s a0 = *(const v8s*)&sCube[ln * 392 + k0 * 32 + q * 8];
            v8s a1 = *(const v8s*)&sCube[(16 + ln) * 392 + k0 * 32 + q * 8];
            acc0 = __builtin_amdgcn_mfma_f32_16x16x32_bf16(a0, b, acc0, 0, 0, 0);
            acc1 = __builtin_amdgcn_mfma_f32_16x16x32_bf16(a1, b, acc1, 0, 0, 0);
        }
        float bias = bcomb[col];
        #pragma unroll
        for (int r = 0; r < 4; r++) {
            xloc[(base + q * 4 + r) * 128 + col]      = f2s(acc0[r] + bias);
            xloc[(base + 16 + q * 4 + r) * 128 + col] = f2s(acc1[r] + bias);
        }
    }
}

// ---- kernel B: fc1 + fc2 + fc3 + fc4 with deep B-prefetch pipelining ----
// __launch_bounds__(256,2): VGPR cap 256 -> allow ping-pong B staging (8 frags in flight).
// sched_barrier(0) pins load-issue before MFMA stream so the compiler can't serialize.
__global__ __launch_bounds__(256, 2) void mlp_kernel(
    const void* __restrict__ v,
    const float* __restrict__ n_accum,
    const short* __restrict__ xloc,
    const short* __restrict__ fc2T,
    const short* __restrict__ fc3T,
    const void* __restrict__ fc1_w, const void* __restrict__ fc1_b,
    const void* __restrict__ fc2_b, const void* __restrict__ fc3_b,
    const void* __restrict__ fc4_w, const void* __restrict__ fc4_b,
    void* __restrict__ out,
    const int* __restrict__ flag)
{
    __shared__ __align__(16) char smem[51712];
    short* sX  = (short*)smem;                 // [32][264]
    short* sH  = (short*)(smem + 16896);       // [32][520]
    short* s3  = (short*)smem;                 // alias sX
    short* sW4 = (short*)(smem + 50176);       // [3][256]

    const int bf = *flag;
    const int t = threadIdx.x;
    const int base = blockIdx.x * TVB;
    const int w = t >> 6, L = t & 63, q = L >> 4, ln = L & 15;

    // x_local coalesced load -> sX cols 128..255
    {
        int flat = t * 16;
        int row = flat >> 7, col = flat & 127;
        const short* src = xloc + (base + row) * 128 + col;
        v8s x0 = *(const v8s*)src;
        v8s x1 = *(const v8s*)(src + 8);
        *(v8s*)&sX[row * 264 + 128 + col]     = x0;
        *(v8s*)&sX[row * 264 + 128 + col + 8] = x1;
    }

    // fc4 weights -> LDS
    for (int i = t; i < 768; i += 256) {
        int j = i >> 8, k = i & 255;
        sW4[i] = f2s(ldf(fc4_w, k * 3 + j, bf));
    }

    // fc1 (6->128): one vertex per thread, 16 cols each
    {
        int vi = t & 31, cb = (t >> 5) * 16;
        int vert = base + vi;
        float i0 = 0.f, i1 = 0.f, i2 = 0.f, i3 = 0.f, i4 = 0.f, i5 = 0.f;
        if (vert < NVERT) {
            i0 = ldf(v, vert * 3 + 0, bf);
            i1 = ldf(v, vert * 3 + 1, bf);
            i2 = ldf(v, vert * 3 + 2, bf);
            float nx = n_accum[vert * 3 + 0];
            float ny = n_accum[vert * 3 + 1];
            float nz = n_accum[vert * 3 + 2];
            float inv = 1.0f / fmaxf(sqrtf(nx * nx + ny * ny + nz * nz), 1e-12f);
            i3 = nx * inv; i4 = ny * inv; i5 = nz * inv;
        }
        #pragma unroll
        for (int i = 0; i < 16; i++) {
            int c = cb + i;
            float acc = ldf(fc1_b, c, bf)
                      + i0 * ldf(fc1_w, 0 * 128 + c, bf)
                      + i1 * ldf(fc1_w, 1 * 128 + c, bf)
                      + i2 * ldf(fc1_w, 2 * 128 + c, bf)
                      + i3 * ldf(fc1_w, 3 * 128 + c, bf)
                      + i4 * ldf(fc1_w, 4 * 128 + c, bf)
                      + i5 * ldf(fc1_w, 5 * 128 + c, bf);
            sX[vi * 264 + c] = f2s(lrelu(acc));
        }
    }
    __syncthreads();

    // ---- fc2: [32x256] @ fc2T^T -> sH [32][512], leaky; A hoisted, B ping-pong 8-deep ----
    {
        v8s a0[8], a1[8];
        #pragma unroll
        for (int k0 = 0; k0 < 8; k0++) {
            a0[k0] = *(const v8s*)&sX[ln * 264 + k0 * 32 + q * 8];
            a1[k0] = *(const v8s*)&sX[(16 + ln) * 264 + k0 * 32 + q * 8];
        }
        v8s bA[8], bB[8];
        {
            const short* bb = fc2T + (w * 128 + ln) * 256;
            #pragma unroll
            for (int k0 = 0; k0 < 8; k0++) bA[k0] = *(const v8s*)(bb + k0 * 32 + q * 8);
        }
        #pragma unroll
        for (int nt = 0; nt < 8; nt++) {
            int col = w * 128 + nt * 16 + ln;
            // prefetch next nt into the other buffer
            if (nt < 7) {
                const short* bbn = fc2T + (col + 16) * 256;
                if (nt & 1) {
                    #pragma unroll
                    for (int k0 = 0; k0 < 8; k0++) bA[k0] = *(const v8s*)(bbn + k0 * 32 + q * 8);
                } else {
                    #pragma unroll
                    for (int k0 = 0; k0 < 8; k0++) bB[k0] = *(const v8s*)(bbn + k0 * 32 + q * 8);
                }
            }
            __builtin_amdgcn_sched_barrier(0);   // loads above stay above the MFMAs below
            v4f acc0 = {0.f, 0.f, 0.f, 0.f}, acc1 = {0.f, 0.f, 0.f, 0.f};
            if (nt & 1) {
                #pragma unroll
                for (int k0 = 0; k0 < 8; k0++) {
                    acc0 = __builtin_amdgcn_mfma_f32_16x16x32_bf16(a0[k0], bB[k0], acc0, 0, 0, 0);
                    acc1 = __builtin_amdgcn_mfma_f32_16x16x32_bf16(a1[k0], bB[k0], acc1, 0, 0, 0);
                }
            } else {
                #pragma unroll
                for (int k0 = 0; k0 < 8; k0++) {
                    acc0 = __builtin_amdgcn_mfma_f32_16x16x32_bf16(a0[k0], bA[k0], acc0, 0, 0, 0);
                    acc1 = __builtin_amdgcn_mfma_f32_16x16x32_bf16(a1[k0], bA[k0], acc1, 0, 0, 0);
                }
            }
            float bias = ldf(fc2_b, col, bf);
            #pragma unroll
            for (int r = 0; r < 4; r++) {
                sH[(q * 4 + r) * 520 + col]      = f2s(lrelu(acc0[r] + bias));
                sH[(16 + q * 4 + r) * 520 + col] = f2s(lrelu(acc1[r] + bias));
            }
        }
    }
    __syncthreads();

    // ---- fc3: [32x512] @ fc3T^T -> s3 [32][256], leaky; half-major, acc persistent, B ping-pong ----
    {
        v4f acc0[4], acc1[4];
        #pragma unroll
        for (int nt = 0; nt < 4; nt++) {
            acc0[nt] = (v4f){0.f, 0.f, 0.f, 0.f};
            acc1[nt] = (v4f){0.f, 0.f, 0.f, 0.f};
        }
        #pragma unroll
        for (int half = 0; half < 2; half++) {
            v8s a0[8], a1[8];
            #pragma unroll
            for (int k0 = 0; k0 < 8; k0++) {
                a0[k0] = *(const v8s*)&sH[ln * 520 + half * 256 + k0 * 32 + q * 8];
                a1[k0] = *(const v8s*)&sH[(16 + ln) * 520 + half * 256 + k0 * 32 + q * 8];
            }
            v8s bA[8], bB[8];
            {
                const short* bb = fc3T + (w * 64 + ln) * 512 + half * 256;
                #pragma unroll
                for (int k0 = 0; k0 < 8; k0++) bA[k0] = *(const v8s*)(bb + k0 * 32 + q * 8);
            }
            #pragma unroll
            for (int nt = 0; nt < 4; nt++) {
                int col = w * 64 + nt * 16 + ln;
                if (nt < 3) {
                    const short* bbn = fc3T + (col + 16) * 512 + half * 256;
                    if (nt & 1) {
                        #pragma unroll
                        for (int k0 = 0; k0 < 8; k0++) bA[k0] = *(const v8s*)(bbn + k0 * 32 + q * 8);
                    } else {
                        #pragma unroll
                        for (int k0 = 0; k0 < 8; k0++) bB[k0] = *(const v8s*)(bbn + k0 * 32 + q * 8);
                    }
                }
                __builtin_amdgcn_sched_barrier(0);
                if (nt & 1) {
                    #pragma unroll
                    for (int k0 = 0; k0 < 8; k0++) {
                        acc0[nt] = __builtin_amdgcn_mfma_f32_16x16x32_bf16(a0[k0], bB[k0], acc0[nt], 0, 0, 0);
                        acc1[nt] = __builtin_amdgcn_mfma_f32_16x16x32_bf16(a1[k0], bB[k0], acc1[nt], 0, 0, 0);
                    }
                } else {
                    #pragma unroll
                    for (int k0 = 0; k0 < 8; k0++) {
                        acc0[nt] = __builtin_amdgcn_mfma_f32_16x16x32_bf16(a0[k0], bA[k0], acc0[nt], 0, 0, 0);
                        acc1[nt] = __builtin_amdgcn_mfma_f32_16x16x32_bf16(a1[k0], bA[k0], acc1[nt], 0, 0, 0);
                    }
                }
            }
        }
        #pragma unroll
        for (int nt = 0; nt < 4; nt++) {
            int col = w * 64 + nt * 16 + ln;
            float bias = ldf(fc3_b, col, bf);
            #pragma unroll
            for (int r = 0; r < 4; r++) {
                s3[(q * 4 + r) * 264 + col]      = f2s(lrelu(acc0[nt][r] + bias));
                s3[(16 + q * 4 + r) * 264 + col] = f2s(lrelu(acc1[nt][r] + bias));
            }
        }
    }
    __syncthreads();

    // fc4 (256->3) + tanh*0.1 + residual
    {
        int vi = t >> 3, l = t & 7;
        float p0a = 0.f, p1a = 0.f, p2a = 0.f, p0b = 0.f, p1b = 0.f, p2b = 0.f;
        for (int k = l; k < 256; k += 16) {
            float a = s2f(s3[vi * 264 + k]);
            float b2 = s2f(s3[vi * 264 + k + 8]);
            p0a += a * s2f(sW4[0 * 256 + k]);
            p1a += a * s2f(sW4[1 * 256 + k]);
            p2a += a * s2f(sW4[2 * 256 + k]);
            p0b += b2 * s2f(sW4[0 * 256 + k + 8]);
            p1b += b2 * s2f(sW4[1 * 256 + k + 8]);
            p2b += b2 * s2f(sW4[2 * 256 + k + 8]);
        }
        float p0 = p0a + p0b, p1 = p1a + p1b, p2 = p2a + p2b;
        #pragma unroll
        for (int s = 4; s; s >>= 1) {
            p0 += __shfl_down(p0, s, 8);
            p1 += __shfl_down(p1, s, 8);
            p2 += __shfl_down(p2, s, 8);
        }
        if (l == 0) {
            int vert = base + vi;
            if (vert < NVERT) {
                float vx = ldf(v, vert * 3 + 0, bf);
                float vy = ldf(v, vert * 3 + 1, bf);
                float vz = ldf(v, vert * 3 + 2, bf);
                float o0 = vx + 0.1f * tanhf(p0 + ldf(fc4_b, 0, bf));
                float o1 = vy + 0.1f * tanhf(p1 + ldf(fc4_b, 1, bf));
                float o2 = vz + 0.1f * tanhf(p2 + ldf(fc4_b, 2, bf));
                if (bf) {
                    short* ob = (short*)out;
                    ob[vert * 3 + 0] = f2s(o0);
                    ob[vert * 3 + 1] = f2s(o1);
                    ob[vert * 3 + 2] = f2s(o2);
                } else {
                    float* of = (float*)out;
                    of[vert * 3 + 0] = o0;
                    of[vert * 3 + 1] = o1;
                    of[vert * 3 + 2] = o2;
                }
            }
        }
    }
}

// ================= SMALL-WS FALLBACK: R10 monolith =================
__global__ __launch_bounds__(256, 3) void fused_mfma_kernel(
    const void* __restrict__ v,
    const float* __restrict__ n_accum,
    const void* __restrict__ volume,
    const short* __restrict__ vol1,
    const short* __restrict__ vol2,
    const short* __restrict__ Wcomb,
    const float* __restrict__ bcomb,
    const short* __restrict__ fc2T,
    const short* __restrict__ fc3T,
    const void* __restrict__ fc1_w, const void* __restrict__ fc1_b,
    const void* __restrict__ fc2_b, const void* __restrict__ fc3_b,
    const void* __restrict__ fc4_w, const void* __restrict__ fc4_b,
    void* __restrict__ out,
    const int* __restrict__ flag)
{
    __shared__ __align__(16) char smem[51712];
    short* sX    = (short*)smem;
    short* sCube = (short*)(smem + 16896);
    short* sH    = (short*)(smem + 16896);
    short* s3    = (short*)smem;
    short* sW4   = (short*)(smem + 50176);

    const int bf = *flag;
    const int t = threadIdx.x;
    const int base = blockIdx.x * TVB;
    const int w = t >> 6, L = t & 63, q = L >> 4, ln = L & 15;

    for (int idx = t; idx < TVB * 75; idx += 256) {
        int vl  = idx / 75;
        int r75 = idx - vl * 75;
        int n   = r75 / 25;
        int dd  = r75 - n * 25;
        int di  = dd / 5, dj = dd - di * 5;
        int vert = base + vl;
        short* dst = &sCube[vl * 392 + n * 125 + dd * 5];
        if (vert < NVERT) {
            float vx = ldf(v, vert * 3 + 0, bf);
            float vy = ldf(v, vert * 3 + 1, bf);
            float vz = ldf(v, vert * 3 + 2, bf);
            float scl = (n == 0) ? 96.0f : (n == 1 ? 48.0f : 24.0f);
            int lim = (LVOL >> n) - 3;
            int cx = (int)rintf((vx + 1.0f) * scl);
            int cy = (int)rintf((vy + 1.0f) * scl);
            int cz = (int)rintf((vz + 1.0f) * scl);
            cx = min(max(cx, 2), lim) + di - 2;
            cy = min(max(cy, 2), lim) + dj - 2;
            cz = min(max(cz, 2), lim);
            if (n == 0) {
                int b0 = (cx * LVOL + cy) * LVOL + (cz - 2);
                if (bf) {
                    const short* vp = (const short*)volume;
                    #pragma unroll
                    for (int i = 0; i < 5; i++) dst[i] = vp[b0 + i];
                } else {
                    const float* vp = (const float*)volume;
                    #pragma unroll
                    for (int i = 0; i < 5; i++) dst[i] = f2s(vp[b0 + i]);
                }
            } else {
                const short* lvl = (n == 1) ? vol1 : vol2;
                int dim = (n == 1) ? 96 : 48;
                int b0 = (cx * dim + cy) * dim + (cz - 2);
                #pragma unroll
                for (int i = 0; i < 5; i++) dst[i] = lvl[b0 + i];
            }
        } else {
            #pragma unroll
            for (int i = 0; i < 5; i++) dst[i] = 0;
        }
    }
    for (int idx = t; idx < TVB * 9; idx += 256) {
        int vl = idx / 9, rr = idx - vl * 9;
        sCube[vl * 392 + 375 + rr] = 0;
    }
    for (int i = t; i < 768; i += 256) {
        int j = i >> 8, k = i & 255;
        sW4[i] = f2s(ldf(fc4_w, k * 3 + j, bf));
    }
    {
        int vi = t & 31, cb = (t >> 5) * 16;
        int vert = base + vi;
        float i0 = 0.f, i1 = 0.f, i2 = 0.f, i3 = 0.f, i4 = 0.f, i5 = 0.f;
        if (vert < NVERT) {
            i0 = ldf(v, vert * 3 + 0, bf);
            i1 = ldf(v, vert * 3 + 1, bf);
            i2 = ldf(v, vert * 3 + 2, bf);
            float nx = n_accum[vert * 3 + 0];
            float ny = n_accum[vert * 3 + 1];
            float nz = n_accum[vert * 3 + 2];
            float inv = 1.0f / fmaxf(sqrtf(nx * nx + ny * ny + nz * nz), 1e-12f);
            i3 = nx * inv; i4 = ny * inv; i5 = nz * inv;
        }
        #pragma unroll
        for (int i = 0; i < 16; i++) {
            int c = cb + i;
            float acc = ldf(fc1_b, c, bf)
                      + i0 * ldf(fc1_w, 0 * 128 + c, bf)
                      + i1 * ldf(fc1_w, 1 * 128 + c, bf)
                      + i2 * ldf(fc1_w, 2 * 128 + c, bf)
                      + i3 * ldf(fc1_w, 3 * 128 + c, bf)
                      + i4 * ldf(fc1_w, 4 * 128 + c, bf)
                      + i5 * ldf(fc1_w, 5 * 128 + c, bf);
            sX[vi * 264 + c] = f2s(lrelu(acc));
        }
    }
    __syncthreads();

    #pragma unroll
    for (int nt = 0; nt < 2; nt++) {
        int col = w * 32 + nt * 16 + ln;
        v4f acc0 = {0.f, 0.f, 0.f, 0.f}, acc1 = {0.f, 0.f, 0.f, 0.f};
        #pragma unroll
        for (int k0 = 0; k0 < 12; k0++) {
            v8s b  = *(const v8s*)&Wcomb[col * 384 + k0 * 32 + q * 8];
            v8s a0 = *(const v8s*)&sCube[ln * 392 + k0 * 32 + q * 8];
            v8s a1 = *(const v8s*)&sCube[(16 + ln) * 392 + k0 * 32 + q * 8];
            acc0 = __builtin_amdgcn_mfma_f32_16x16x32_bf16(a0, b, acc0, 0, 0, 0);
            acc1 = __builtin_amdgcn_mfma_f32_16x16x32_bf16(a1, b, acc1, 0, 0, 0);
        }
        float bias = bcomb[col];
        #pragma unroll
        for (int r = 0; r < 4; r++) {
            sX[(q * 4 + r) * 264 + 128 + col]      = f2s(acc0[r] + bias);
            sX[(16 + q * 4 + r) * 264 + 128 + col] = f2s(acc1[r] + bias);
        }
    }
    __syncthreads();

    {
        v8s a0[8], a1[8];
        #pragma unroll
        for (int k0 = 0; k0 < 8; k0++) {
            a0[k0] = *(const v8s*)&sX[ln * 264 + k0 * 32 + q * 8];
            a1[k0] = *(const v8s*)&sX[(16 + ln) * 264 + k0 * 32 + q * 8];
        }
        #pragma unroll
        for (int nt = 0; nt < 8; nt++) {
            int col = w * 128 + nt * 16 + ln;
            const short* bb = fc2T + col * 256;
            v4f acc0 = {0.f, 0.f, 0.f, 0.f}, acc1 = {0.f, 0.f, 0.f, 0.f};
            #pragma unroll
            for (int k0 = 0; k0 < 8; k0++) {
                v8s b = *(const v8s*)(bb + k0 * 32 + q * 8);
                acc0 = __builtin_amdgcn_mfma_f32_16x16x32_bf16(a0[k0], b, acc0, 0, 0, 0);
                acc1 = __builtin_amdgcn_mfma_f32_16x16x32_bf16(a1[k0], b, acc1, 0, 0, 0);
            }
            float bias = ldf(fc2_b, col, bf);
            #pragma unroll
            for (int r = 0; r < 4; r++) {
                sH[(q * 4 + r) * 520 + col]      = f2s(lrelu(acc0[r] + bias));
                sH[(16 + q * 4 + r) * 520 + col] = f2s(lrelu(acc1[r] + bias));
            }
        }
    }
    __syncthreads();

    {
        #pragma unroll
        for (int nt = 0; nt < 4; nt++) {
            int col = w * 64 + nt * 16 + ln;
            v4f acc0 = {0.f, 0.f, 0.f, 0.f}, acc1 = {0.f, 0.f, 0.f, 0.f};
            #pragma unroll
            for (int half = 0; half < 2; half++) {
                const short* bb = fc3T + col * 512 + half * 256;
                #pragma unroll
                for (int k0 = 0; k0 < 8; k0++) {
                    v8s b  = *(const v8s*)(bb + k0 * 32 + q * 8);
                    v8s a0 = *(const v8s*)&sH[ln * 520 + half * 256 + k0 * 32 + q * 8];
                    v8s a1 = *(const v8s*)&sH[(16 + ln) * 520 + half * 256 + k0 * 32 + q * 8];
                    acc0 = __builtin_amdgcn_mfma_f32_16x16x32_bf16(a0, b, acc0, 0, 0, 0);
                    acc1 = __builtin_amdgcn_mfma_f32_16x16x32_bf16(a1, b, acc1, 0, 0, 0);
                }
            }
            float bias = ldf(fc3_b, col, bf);
            #pragma unroll
            for (int r = 0; r < 4; r++) {
                s3[(q * 4 + r) * 264 + col]      = f2s(lrelu(acc0[r] + bias));
                s3[(16 + q * 4 + r) * 264 + col] = f2s(lrelu(acc1[r] + bias));
            }
        }
    }
    __syncthreads();

    {
        int vi = t >> 3, l = t & 7;
        float p0 = 0.f, p1 = 0.f, p2 = 0.f;
        for (int k = l; k < 256; k += 8) {
            float a = s2f(s3[vi * 264 + k]);
            p0 += a * s2f(sW4[0 * 256 + k]);
            p1 += a * s2f(sW4[1 * 256 + k]);
            p2 += a * s2f(sW4[2 * 256 + k]);
        }
        #pragma unroll
        for (int s = 4; s; s >>= 1) {
            p0 += __shfl_down(p0, s, 8);
            p1 += __shfl_down(p1, s, 8);
            p2 += __shfl_down(p2, s, 8);
        }
        if (l == 0) {
            int vert = base + vi;
            if (vert < NVERT) {
                float vx = ldf(v, vert * 3 + 0, bf);
                float vy = ldf(v, vert * 3 + 1, bf);
                float vz = ldf(v, vert * 3 + 2, bf);
                float o0 = vx + 0.1f * tanhf(p0 + ldf(fc4_b, 0, bf));
                float o1 = vy + 0.1f * tanhf(p1 + ldf(fc4_b, 1, bf));
                float o2 = vz + 0.1f * tanhf(p2 + ldf(fc4_b, 2, bf));
                if (bf) {
                    short* ob = (short*)out;
                    ob[vert * 3 + 0] = f2s(o0);
                    ob[vert * 3 + 1] = f2s(o1);
                    ob[vert * 3 + 2] = f2s(o2);
                } else {
                    float* of = (float*)out;
                    of[vert * 3 + 0] = o0;
                    of[vert * 3 + 1] = o1;
                    of[vert * 3 + 2] = o2;
                }
            }
        }
    }
}

extern "C" void kernel_launch(void* const* d_in, const int* in_sizes, int n_in,
                              void* d_out, int out_size, void* d_ws, size_t ws_size,
                              hipStream_t stream) {
    const void* v      = d_in[0];
    const int*  f      = (const int*)d_in[1];
    const void* volume = d_in[2];
    const void* fc1_w  = d_in[3];
    const void* fc1_b  = d_in[4];
    const void* fc2_w  = d_in[5];
    const void* fc2_b  = d_in[6];
    const void* fc3_w  = d_in[7];
    const void* fc3_b  = d_in[8];
    const void* fc4_w  = d_in[9];
    const void* fc4_b  = d_in[10];
    const void* conv_w = d_in[11];
    const void* conv_b = d_in[12];
    const void* lfc_w  = d_in[13];
    const void* lfc_b  = d_in[14];

    char* wsb = (char*)d_ws;
    const int big = (ws_size >= WS_BIG_NEED) ? 1 : 0;

    if (big) {
        int*   flag    = (int*)wsb;
        float* n_accum = (float*)(wsb + 64);
        float* vol1f   = (float*)(wsb + 1800064);
        float* vol2f   = (float*)(wsb + 5339008);
        short* Wcomb   = (short*)(wsb + 5781376);
        float* bcomb   = (float*)(wsb + 5879680);
        short* fc2T    = (short*)(wsb + 5880192);
        short* fc3T    = (short*)(wsb + 6142336);
        short* xloc    = (short*)(wsb + 6404480);

        hipMemsetAsync(n_accum, 0, NVERT * 3 * sizeof(float), stream);
        detect_kernel<<<1, 256, 0, stream>>>(v, flag);
        mega_prep_kernel<<<NB_MEGA, 256, 0, stream>>>(
            v, f, n_accum, volume,
            (short*)wsb, vol1f, (short*)wsb, vol2f,
            fc2_w, fc3_w, fc2T, fc3T,
            conv_w, lfc_w, conv_b, lfc_b, Wcomb, bcomb, flag, 1);
        gather_conv_kernel<<<(NVERT + TVB - 1) / TVB, 256, 0, stream>>>(
            v, volume, vol1f, vol2f, Wcomb, bcomb, xloc, flag);
        mlp_kernel<<<(NVERT + TVB - 1) / TVB, 256, 0, stream>>>(
            v, n_accum, xloc, fc2T, fc3T,
            fc1_w, fc1_b, fc2_b, fc3_b, fc4_w, fc4_b, d_out, flag);
    } else {
        int*   flag    = (int*)wsb;
        float* n_accum = (float*)(wsb + 64);
        short* vol1    = (short*)(wsb + 1800064);
        short* vol2    = (short*)(wsb + 3569536);
        short* Wcomb   = (short*)(wsb + 3790720);
        float* bcomb   = (float*)(wsb + 3889024);
        short* fc2T    = (short*)(wsb + 3889536);
        short* fc3T    = (short*)(wsb + 4151680);

        hipMemsetAsync(n_accum, 0, NVERT * 3 * sizeof(float), stream);
        detect_kernel<<<1, 256, 0, stream>>>(v, flag);
        mega_prep_kernel<<<NB_MEGA, 256, 0, stream>>>(
            v, f, n_accum, volume,
            vol1, (float*)wsb, vol2, (float*)wsb,
            fc2_w, fc3_w, fc2T, fc3T,
            conv_w, lfc_w, conv_b, lfc_b, Wcomb, bcomb, flag, 0);
        fused_mfma_kernel<<<(NVERT + TVB - 1) / TVB, 256, 0, stream>>>(
            v, n_accum, volume, vol1, vol2, Wcomb, bcomb, fc2T, fc3T,
            fc1_w, fc1_b, fc2_b, fc3_b, fc4_w, fc4_b, d_out, flag);
    }
}

// Round 13
// 689.089 us; speedup vs baseline: 1.0938x; 1.0938x over previous
//
#include <hip/hip_runtime.h>
#include <hip/hip_bf16.h>
#include <math.h>

#define NVERT 150000
#define NFACE 300000
#define LVOL  192
#define TVB   32
#define MTV   48      // vertices per block in mlp kernel (M = 3 MFMA rows)

// mega_prep block-range partition
#define NB_NORM   1172
#define NB_POOL1  3456
#define NB_POOL2  432
#define NB_PW     1024
#define NB_PC     193
#define POOL1_START (NB_NORM)
#define POOL2_START (NB_NORM + NB_POOL1)
#define PW_START    (NB_NORM + NB_POOL1 + NB_POOL2)
#define PC_START    (NB_NORM + NB_POOL1 + NB_POOL2 + NB_PW)
#define NB_MEGA     (NB_NORM + NB_POOL1 + NB_POOL2 + NB_PW + NB_PC)

#define WS_BIG_NEED 44808576ull

typedef short v8s __attribute__((ext_vector_type(8)));
typedef float v4f __attribute__((ext_vector_type(4)));

__device__ __forceinline__ float s2f(short s) {
    unsigned int u = ((unsigned int)(unsigned short)s) << 16;
    return __builtin_bit_cast(float, u);
}
__device__ __forceinline__ short f2s(float f) {
    __hip_bfloat16 h = __float2bfloat16(f);
    return __builtin_bit_cast(short, h);
}
__device__ __forceinline__ float lrelu(float x) { return x > 0.f ? x : 0.15f * x; }

__device__ __forceinline__ float ldf(const void* __restrict__ p, int i, int bf) {
    return bf ? s2f(((const short*)p)[i]) : ((const float*)p)[i];
}

// ---- detect input dtype (bf16 vs fp32) ----
__global__ void detect_kernel(const void* __restrict__ v, int* __restrict__ flag) {
    __shared__ int s_ok;
    int t = threadIdx.x;
    if (t == 0) s_ok = 1;
    __syncthreads();
    float x = s2f(((const short*)v)[t]);
    if (!(fabsf(x) <= 1.0f)) atomicAnd(&s_ok, 0);
    __syncthreads();
    if (t == 0) *flag = s_ok;
}

// ---------------- mega prep: normals | pool1 | pool2-direct | transposes | Wcomb ----------------
__global__ __launch_bounds__(256) void mega_prep_kernel(
    const void* __restrict__ v, const int* __restrict__ f, float* __restrict__ n_accum,
    const void* __restrict__ volume,
    short* __restrict__ vol1b, float* __restrict__ vol1f,
    short* __restrict__ vol2b, float* __restrict__ vol2f,
    const void* __restrict__ fc2_w, const void* __restrict__ fc3_w,
    short* __restrict__ fc2T, short* __restrict__ fc3T,
    const void* __restrict__ conv_w, const void* __restrict__ lfc_w,
    const void* __restrict__ conv_b, const void* __restrict__ lfc_b,
    short* __restrict__ Wcomb, float* __restrict__ bcomb,
    const int* __restrict__ flag, int bigws)
{
    const int bf = *flag;
    const int bid = blockIdx.x;
    const int t = threadIdx.x;

    if (bid < NB_NORM) {
        int ft = bid * 256 + t;
        if (ft >= NFACE) return;
        int i0 = f[ft * 3 + 0], i1 = f[ft * 3 + 1], i2 = f[ft * 3 + 2];
        float p0x = ldf(v, i0 * 3 + 0, bf), p0y = ldf(v, i0 * 3 + 1, bf), p0z = ldf(v, i0 * 3 + 2, bf);
        float p1x = ldf(v, i1 * 3 + 0, bf), p1y = ldf(v, i1 * 3 + 1, bf), p1z = ldf(v, i1 * 3 + 2, bf);
        float p2x = ldf(v, i2 * 3 + 0, bf), p2y = ldf(v, i2 * 3 + 1, bf), p2z = ldf(v, i2 * 3 + 2, bf);
        float e1x = p1x - p0x, e1y = p1y - p0y, e1z = p1z - p0z;
        float e2x = p2x - p0x, e2y = p2y - p0y, e2z = p2z - p0z;
        float cx = e1y * e2z - e1z * e2y;
        float cy = e1z * e2x - e1x * e2z;
        float cz = e1x * e2y - e1y * e2x;
        atomicAdd(&n_accum[i0 * 3 + 0], cx); atomicAdd(&n_accum[i0 * 3 + 1], cy); atomicAdd(&n_accum[i0 * 3 + 2], cz);
        atomicAdd(&n_accum[i1 * 3 + 0], cx); atomicAdd(&n_accum[i1 * 3 + 1], cy); atomicAdd(&n_accum[i1 * 3 + 2], cz);
        atomicAdd(&n_accum[i2 * 3 + 0], cx); atomicAdd(&n_accum[i2 * 3 + 1], cy); atomicAdd(&n_accum[i2 * 3 + 2], cz);
    } else if (bid < POOL2_START) {
        int id = (bid - POOL1_START) * 256 + t;
        int z = id % 96, y = (id / 96) % 96, x = id / (96 * 96);
        float s = 0.f;
        #pragma unroll
        for (int a = 0; a < 2; a++)
            #pragma unroll
            for (int b = 0; b < 2; b++)
                #pragma unroll
                for (int c = 0; c < 2; c++)
                    s += ldf(volume, (2 * x + a) * (LVOL * LVOL) + (2 * y + b) * LVOL + (2 * z + c), bf);
        s *= 0.125f;
        if (bigws) vol1f[id] = s; else vol1b[id] = f2s(s);
    } else if (bid < PW_START) {
        int id = (bid - POOL2_START) * 256 + t;
        int z = id % 48, y = (id / 48) % 48, x = id / (48 * 48);
        float s = 0.f;
        for (int a = 0; a < 4; a++)
            for (int b = 0; b < 4; b++)
                #pragma unroll
                for (int c = 0; c < 4; c++)
                    s += ldf(volume, (4 * x + a) * (LVOL * LVOL) + (4 * y + b) * LVOL + (4 * z + c), bf);
        s *= 0.015625f;
        if (bigws) vol2f[id] = s; else vol2b[id] = f2s(s);
    } else if (bid < PC_START) {
        int id = (bid - PW_START) * 256 + t;
        if (id < 131072) {
            int j = id >> 8, k = id & 255;
            fc2T[id] = f2s(ldf(fc2_w, k * 512 + j, bf));
        } else {
            int i = id - 131072;
            int j = i >> 9, k = i & 511;
            fc3T[i] = f2s(ldf(fc3_w, k * 256 + j, bf));
        }
    } else {
        int id = (bid - PC_START) * 256 + t;
        if (id < 49152) {
            int j = id / 384, k = id - j * 384;
            float acc = 0.f;
            if (k < 375) {
                float a0 = 0.f, a1 = 0.f, a2 = 0.f, a3 = 0.f;
                for (int o = 0; o < 128; o += 4) {
                    a0 += ldf(conv_w, (o + 0) * 375 + k, bf) * ldf(lfc_w, (o + 0) * 128 + j, bf);
                    a1 += ldf(conv_w, (o + 1) * 375 + k, bf) * ldf(lfc_w, (o + 1) * 128 + j, bf);
                    a2 += ldf(conv_w, (o + 2) * 375 + k, bf) * ldf(lfc_w, (o + 2) * 128 + j, bf);
                    a3 += ldf(conv_w, (o + 3) * 375 + k, bf) * ldf(lfc_w, (o + 3) * 128 + j, bf);
                }
                acc = (a0 + a1) + (a2 + a3);
            }
            Wcomb[j * 384 + k] = f2s(acc);
        } else if (id < 49152 + 128) {
            int j = id - 49152;
            float acc = ldf(lfc_b, j, bf);
            for (int o = 0; o < 128; o++) acc += ldf(conv_b, o, bf) * ldf(lfc_w, o * 128 + j, bf);
            bcomb[j] = acc;
        }
    }
}

// ================= BIG-WS SPLIT PATH =================

// ---- kernel A: gather + conv GEMM -> xloc global ----
__global__ __launch_bounds__(256, 6) void gather_conv_kernel(
    const void* __restrict__ v,
    const void* __restrict__ volume,
    const float* __restrict__ vol1f,
    const float* __restrict__ vol2f,
    const short* __restrict__ Wcomb,
    const float* __restrict__ bcomb,
    short* __restrict__ xloc,
    const int* __restrict__ flag)
{
    __shared__ __align__(16) short sCube[TVB * 392];
    __shared__ int sIdx[TVB * 4];

    const int bf = *flag;
    const int t = threadIdx.x;
    const int base = blockIdx.x * TVB;
    const int w = t >> 6, L = t & 63, q = L >> 4, ln = L & 15;

    if (t < TVB) {
        int vert = min(base + t, NVERT - 1);
        float vx = ldf(v, vert * 3 + 0, bf);
        float vy = ldf(v, vert * 3 + 1, bf);
        float vz = ldf(v, vert * 3 + 2, bf);
        #pragma unroll
        for (int n = 0; n < 3; n++) {
            float scl = (n == 0) ? 96.0f : (n == 1 ? 48.0f : 24.0f);
            int dim = LVOL >> n, lim = dim - 3;
            int cx = min(max((int)rintf((vx + 1.0f) * scl), 2), lim);
            int cy = min(max((int)rintf((vy + 1.0f) * scl), 2), lim);
            int cz = min(max((int)rintf((vz + 1.0f) * scl), 2), lim);
            sIdx[t * 4 + n] = (cx * dim + cy) * dim + (cz - 2);
        }
    }
    __syncthreads();

    for (int idx = t; idx < TVB * 75; idx += 256) {
        int n   = idx / 800;
        int rem = idx - n * 800;
        int vl  = rem / 25;
        int dd  = rem - vl * 25;
        int di  = dd / 5, dj = dd - di * 5;
        int dim = LVOL >> n;
        int addr = sIdx[vl * 4 + n] + (di - 2) * dim * dim + (dj - 2) * dim;
        short* dst = &sCube[vl * 392 + n * 125 + dd * 5];
        if (n == 0) {
            if (bf) {
                const short* vp = (const short*)volume;
                #pragma unroll
                for (int i = 0; i < 5; i++) dst[i] = vp[addr + i];
            } else {
                const float* vp = (const float*)volume;
                #pragma unroll
                for (int i = 0; i < 5; i++) dst[i] = f2s(vp[addr + i]);
            }
        } else {
            const float* lvl = (n == 1) ? vol1f : vol2f;
            #pragma unroll
            for (int i = 0; i < 5; i++) dst[i] = f2s(lvl[addr + i]);
        }
    }
    for (int idx = t; idx < TVB * 9; idx += 256) {
        int vl = idx / 9, rr = idx - vl * 9;
        sCube[vl * 392 + 375 + rr] = 0;
    }
    __syncthreads();

    #pragma unroll
    for (int nt = 0; nt < 2; nt++) {
        int col = w * 32 + nt * 16 + ln;
        v4f acc0 = {0.f, 0.f, 0.f, 0.f}, acc1 = {0.f, 0.f, 0.f, 0.f};
        #pragma unroll
        for (int k0 = 0; k0 < 12; k0++) {
            v8s b  = *(const v8s*)&Wcomb[col * 384 + k0 * 32 + q * 8];
            v8s a0 = *(const v8s*)&sCube[ln * 392 + k0 * 32 + q * 8];
            v8s a1 = *(const v8s*)&sCube[(16 + ln) * 392 + k0 * 32 + q * 8];
            acc0 = __builtin_amdgcn_mfma_f32_16x16x32_bf16(a0, b, acc0, 0, 0, 0);
            acc1 = __builtin_amdgcn_mfma_f32_16x16x32_bf16(a1, b, acc1, 0, 0, 0);
        }
        float bias = bcomb[col];
        #pragma unroll
        for (int r = 0; r < 4; r++) {
            xloc[(base + q * 4 + r) * 128 + col]      = f2s(acc0[r] + bias);
            xloc[(base + 16 + q * 4 + r) * 128 + col] = f2s(acc1[r] + bias);
        }
    }
}

// ---- kernel B: MLP, 48 verts/block (M=3 MFMA rows -> 1.5x MFMA per B-load, 2/3 L2 traffic) ----
// LDS 76.8 KB -> 2 blocks/CU; A read from LDS per use (no hoist) keeps VGPR <=128 for 4 waves/SIMD.
__global__ __launch_bounds__(256, 4) void mlp_kernel(
    const void* __restrict__ v,
    const float* __restrict__ n_accum,
    const short* __restrict__ xloc,
    const short* __restrict__ fc2T,
    const short* __restrict__ fc3T,
    const void* __restrict__ fc1_w, const void* __restrict__ fc1_b,
    const void* __restrict__ fc2_b, const void* __restrict__ fc3_b,
    const void* __restrict__ fc4_w, const void* __restrict__ fc4_b,
    void* __restrict__ out,
    const int* __restrict__ flag)
{
    __shared__ __align__(16) char smem[76800];
    short* sX  = (short*)smem;                 // [48][264]  (25,344 B)
    short* sH  = (short*)(smem + 25344);       // [48][520]  (49,920 B)
    short* s3  = (short*)smem;                 // alias sX
    short* sW4 = (short*)(smem + 75264);       // [3][256]   (1,536 B)

    const int bf = *flag;
    const int t = threadIdx.x;
    const int base = blockIdx.x * MTV;         // grid is exact: 150000 = 48 * 3125
    const int w = t >> 6, L = t & 63, q = L >> 4, ln = L & 15;

    // x_local -> sX cols 128..255 (48 rows x 16 v8s = 768 chunks, 3 per thread, coalesced)
    for (int id = t; id < MTV * 16; id += 256) {
        int row = id >> 4, seg = id & 15;
        v8s x = *(const v8s*)(xloc + (base + row) * 128 + seg * 8);
        *(v8s*)&sX[row * 264 + 128 + seg * 8] = x;
    }

    // fc4 weights -> LDS
    for (int i = t; i < 768; i += 256) {
        int j = i >> 8, k = i & 255;
        sW4[i] = f2s(ldf(fc4_w, k * 3 + j, bf));
    }

    // fc1 (6->128): 4 threads per vertex, 32 cols each (vi<48 of 64 slots)
    {
        int vi = t >> 2, cb = (t & 3) * 32;
        if (vi < MTV) {
            int vert = base + vi;
            float i0 = ldf(v, vert * 3 + 0, bf);
            float i1 = ldf(v, vert * 3 + 1, bf);
            float i2 = ldf(v, vert * 3 + 2, bf);
            float nx = n_accum[vert * 3 + 0];
            float ny = n_accum[vert * 3 + 1];
            float nz = n_accum[vert * 3 + 2];
            float inv = 1.0f / fmaxf(sqrtf(nx * nx + ny * ny + nz * nz), 1e-12f);
            float i3 = nx * inv, i4 = ny * inv, i5 = nz * inv;
            #pragma unroll 8
            for (int i = 0; i < 32; i++) {
                int c = cb + i;
                float acc = ldf(fc1_b, c, bf)
                          + i0 * ldf(fc1_w, 0 * 128 + c, bf)
                          + i1 * ldf(fc1_w, 1 * 128 + c, bf)
                          + i2 * ldf(fc1_w, 2 * 128 + c, bf)
                          + i3 * ldf(fc1_w, 3 * 128 + c, bf)
                          + i4 * ldf(fc1_w, 4 * 128 + c, bf)
                          + i5 * ldf(fc1_w, 5 * 128 + c, bf);
                sX[vi * 264 + c] = f2s(lrelu(acc));
            }
        }
    }
    __syncthreads();

    // ---- fc2: [48x256] @ fc2T^T -> sH [48][520], leaky; 3 M-rows per wave ----
    #pragma unroll
    for (int nt = 0; nt < 8; nt++) {
        int col = w * 128 + nt * 16 + ln;
        const short* bb = fc2T + col * 256;
        v4f acc0 = {0.f, 0.f, 0.f, 0.f}, acc1 = {0.f, 0.f, 0.f, 0.f}, acc2 = {0.f, 0.f, 0.f, 0.f};
        #pragma unroll
        for (int k0 = 0; k0 < 8; k0++) {
            v8s b = *(const v8s*)(bb + k0 * 32 + q * 8);
            v8s a0 = *(const v8s*)&sX[(ln) * 264 + k0 * 32 + q * 8];
            v8s a1 = *(const v8s*)&sX[(16 + ln) * 264 + k0 * 32 + q * 8];
            v8s a2 = *(const v8s*)&sX[(32 + ln) * 264 + k0 * 32 + q * 8];
            acc0 = __builtin_amdgcn_mfma_f32_16x16x32_bf16(a0, b, acc0, 0, 0, 0);
            acc1 = __builtin_amdgcn_mfma_f32_16x16x32_bf16(a1, b, acc1, 0, 0, 0);
            acc2 = __builtin_amdgcn_mfma_f32_16x16x32_bf16(a2, b, acc2, 0, 0, 0);
        }
        float bias = ldf(fc2_b, col, bf);
        #pragma unroll
        for (int r = 0; r < 4; r++) {
            sH[(q * 4 + r) * 520 + col]      = f2s(lrelu(acc0[r] + bias));
            sH[(16 + q * 4 + r) * 520 + col] = f2s(lrelu(acc1[r] + bias));
            sH[(32 + q * 4 + r) * 520 + col] = f2s(lrelu(acc2[r] + bias));
        }
    }
    __syncthreads();

    // ---- fc3: [48x512] @ fc3T^T -> s3 [48][264], leaky; 3 M-rows per wave ----
    #pragma unroll
    for (int nt = 0; nt < 4; nt++) {
        int col = w * 64 + nt * 16 + ln;
        const short* bb = fc3T + col * 512;
        v4f acc0 = {0.f, 0.f, 0.f, 0.f}, acc1 = {0.f, 0.f, 0.f, 0.f}, acc2 = {0.f, 0.f, 0.f, 0.f};
        #pragma unroll
        for (int k0 = 0; k0 < 16; k0++) {
            v8s b = *(const v8s*)(bb + k0 * 32 + q * 8);
            v8s a0 = *(const v8s*)&sH[(ln) * 520 + k0 * 32 + q * 8];
            v8s a1 = *(const v8s*)&sH[(16 + ln) * 520 + k0 * 32 + q * 8];
            v8s a2 = *(const v8s*)&sH[(32 + ln) * 520 + k0 * 32 + q * 8];
            acc0 = __builtin_amdgcn_mfma_f32_16x16x32_bf16(a0, b, acc0, 0, 0, 0);
            acc1 = __builtin_amdgcn_mfma_f32_16x16x32_bf16(a1, b, acc1, 0, 0, 0);
            acc2 = __builtin_amdgcn_mfma_f32_16x16x32_bf16(a2, b, acc2, 0, 0, 0);
        }
        float bias = ldf(fc3_b, col, bf);
        #pragma unroll
        for (int r = 0; r < 4; r++) {
            s3[(q * 4 + r) * 264 + col]      = f2s(lrelu(acc0[r] + bias));
            s3[(16 + q * 4 + r) * 264 + col] = f2s(lrelu(acc1[r] + bias));
            s3[(32 + q * 4 + r) * 264 + col] = f2s(lrelu(acc2[r] + bias));
        }
    }
    __syncthreads();

    // ---- fc4 (256->3) + tanh*0.1 + residual; 4 threads per vertex (vi<48 of 64) ----
    {
        int vi = t >> 2, l = t & 3;
        if (vi < MTV) {
            float p0 = 0.f, p1 = 0.f, p2 = 0.f;
            for (int k = l * 8; k < 256; k += 32) {
                #pragma unroll
                for (int j = 0; j < 8; j++) {
                    float a = s2f(s3[vi * 264 + k + j]);
                    p0 += a * s2f(sW4[0 * 256 + k + j]);
                    p1 += a * s2f(sW4[1 * 256 + k + j]);
                    p2 += a * s2f(sW4[2 * 256 + k + j]);
                }
            }
            #pragma unroll
            for (int s = 2; s; s >>= 1) {
                p0 += __shfl_down(p0, s, 4);
                p1 += __shfl_down(p1, s, 4);
                p2 += __shfl_down(p2, s, 4);
            }
            if (l == 0) {
                int vert = base + vi;
                float vx = ldf(v, vert * 3 + 0, bf);
                float vy = ldf(v, vert * 3 + 1, bf);
                float vz = ldf(v, vert * 3 + 2, bf);
                float o0 = vx + 0.1f * tanhf(p0 + ldf(fc4_b, 0, bf));
                float o1 = vy + 0.1f * tanhf(p1 + ldf(fc4_b, 1, bf));
                float o2 = vz + 0.1f * tanhf(p2 + ldf(fc4_b, 2, bf));
                if (bf) {
                    short* ob = (short*)out;
                    ob[vert * 3 + 0] = f2s(o0);
                    ob[vert * 3 + 1] = f2s(o1);
                    ob[vert * 3 + 2] = f2s(o2);
                } else {
                    float* of = (float*)out;
                    of[vert * 3 + 0] = o0;
                    of[vert * 3 + 1] = o1;
                    of[vert * 3 + 2] = o2;
                }
            }
        }
    }
}

// ================= SMALL-WS FALLBACK: R10 monolith =================
__global__ __launch_bounds__(256, 3) void fused_mfma_kernel(
    const void* __restrict__ v,
    const float* __restrict__ n_accum,
    const void* __restrict__ volume,
    const short* __restrict__ vol1,
    const short* __restrict__ vol2,
    const short* __restrict__ Wcomb,
    const float* __restrict__ bcomb,
    const short* __restrict__ fc2T,
    const short* __restrict__ fc3T,
    const void* __restrict__ fc1_w, const void* __restrict__ fc1_b,
    const void* __restrict__ fc2_b, const void* __restrict__ fc3_b,
    const void* __restrict__ fc4_w, const void* __restrict__ fc4_b,
    void* __restrict__ out,
    const int* __restrict__ flag)
{
    __shared__ __align__(16) char smem[51712];
    short* sX    = (short*)smem;
    short* sCube = (short*)(smem + 16896);
    short* sH    = (short*)(smem + 16896);
    short* s3    = (short*)smem;
    short* sW4   = (short*)(smem + 50176);

    const int bf = *flag;
    const int t = threadIdx.x;
    const int base = blockIdx.x * TVB;
    const int w = t >> 6, L = t & 63, q = L >> 4, ln = L & 15;

    for (int idx = t; idx < TVB * 75; idx += 256) {
        int vl  = idx / 75;
        int r75 = idx - vl * 75;
        int n   = r75 / 25;
        int dd  = r75 - n * 25;
        int di  = dd / 5, dj = dd - di * 5;
        int vert = base + vl;
        short* dst = &sCube[vl * 392 + n * 125 + dd * 5];
        if (vert < NVERT) {
            float vx = ldf(v, vert * 3 + 0, bf);
            float vy = ldf(v, vert * 3 + 1, bf);
            float vz = ldf(v, vert * 3 + 2, bf);
            float scl = (n == 0) ? 96.0f : (n == 1 ? 48.0f : 24.0f);
            int lim = (LVOL >> n) - 3;
            int cx = (int)rintf((vx + 1.0f) * scl);
            int cy = (int)rintf((vy + 1.0f) * scl);
            int cz = (int)rintf((vz + 1.0f) * scl);
            cx = min(max(cx, 2), lim) + di - 2;
            cy = min(max(cy, 2), lim) + dj - 2;
            cz = min(max(cz, 2), lim);
            if (n == 0) {
                int b0 = (cx * LVOL + cy) * LVOL + (cz - 2);
                if (bf) {
                    const short* vp = (const short*)volume;
                    #pragma unroll
                    for (int i = 0; i < 5; i++) dst[i] = vp[b0 + i];
                } else {
                    const float* vp = (const float*)volume;
                    #pragma unroll
                    for (int i = 0; i < 5; i++) dst[i] = f2s(vp[b0 + i]);
                }
            } else {
                const short* lvl = (n == 1) ? vol1 : vol2;
                int dim = (n == 1) ? 96 : 48;
                int b0 = (cx * dim + cy) * dim + (cz - 2);
                #pragma unroll
                for (int i = 0; i < 5; i++) dst[i] = lvl[b0 + i];
            }
        } else {
            #pragma unroll
            for (int i = 0; i < 5; i++) dst[i] = 0;
        }
    }
    for (int idx = t; idx < TVB * 9; idx += 256) {
        int vl = idx / 9, rr = idx - vl * 9;
        sCube[vl * 392 + 375 + rr] = 0;
    }
    for (int i = t; i < 768; i += 256) {
        int j = i >> 8, k = i & 255;
        sW4[i] = f2s(ldf(fc4_w, k * 3 + j, bf));
    }
    {
        int vi = t & 31, cb = (t >> 5) * 16;
        int vert = base + vi;
        float i0 = 0.f, i1 = 0.f, i2 = 0.f, i3 = 0.f, i4 = 0.f, i5 = 0.f;
        if (vert < NVERT) {
            i0 = ldf(v, vert * 3 + 0, bf);
            i1 = ldf(v, vert * 3 + 1, bf);
            i2 = ldf(v, vert * 3 + 2, bf);
            float nx = n_accum[vert * 3 + 0];
            float ny = n_accum[vert * 3 + 1];
            float nz = n_accum[vert * 3 + 2];
            float inv = 1.0f / fmaxf(sqrtf(nx * nx + ny * ny + nz * nz), 1e-12f);
            i3 = nx * inv; i4 = ny * inv; i5 = nz * inv;
        }
        #pragma unroll
        for (int i = 0; i < 16; i++) {
            int c = cb + i;
            float acc = ldf(fc1_b, c, bf)
                      + i0 * ldf(fc1_w, 0 * 128 + c, bf)
                      + i1 * ldf(fc1_w, 1 * 128 + c, bf)
                      + i2 * ldf(fc1_w, 2 * 128 + c, bf)
                      + i3 * ldf(fc1_w, 3 * 128 + c, bf)
                      + i4 * ldf(fc1_w, 4 * 128 + c, bf)
                      + i5 * ldf(fc1_w, 5 * 128 + c, bf);
            sX[vi * 264 + c] = f2s(lrelu(acc));
        }
    }
    __syncthreads();

    #pragma unroll
    for (int nt = 0; nt < 2; nt++) {
        int col = w * 32 + nt * 16 + ln;
        v4f acc0 = {0.f, 0.f, 0.f, 0.f}, acc1 = {0.f, 0.f, 0.f, 0.f};
        #pragma unroll
        for (int k0 = 0; k0 < 12; k0++) {
            v8s b  = *(const v8s*)&Wcomb[col * 384 + k0 * 32 + q * 8];
            v8s a0 = *(const v8s*)&sCube[ln * 392 + k0 * 32 + q * 8];
            v8s a1 = *(const v8s*)&sCube[(16 + ln) * 392 + k0 * 32 + q * 8];
            acc0 = __builtin_amdgcn_mfma_f32_16x16x32_bf16(a0, b, acc0, 0, 0, 0);
            acc1 = __builtin_amdgcn_mfma_f32_16x16x32_bf16(a1, b, acc1, 0, 0, 0);
        }
        float bias = bcomb[col];
        #pragma unroll
        for (int r = 0; r < 4; r++) {
            sX[(q * 4 + r) * 264 + 128 + col]      = f2s(acc0[r] + bias);
            sX[(16 + q * 4 + r) * 264 + 128 + col] = f2s(acc1[r] + bias);
        }
    }
    __syncthreads();

    {
        v8s a0[8], a1[8];
        #pragma unroll
        for (int k0 = 0; k0 < 8; k0++) {
            a0[k0] = *(const v8s*)&sX[ln * 264 + k0 * 32 + q * 8];
            a1[k0] = *(const v8s*)&sX[(16 + ln) * 264 + k0 * 32 + q * 8];
        }
        #pragma unroll
        for (int nt = 0; nt < 8; nt++) {
            int col = w * 128 + nt * 16 + ln;
            const short* bb = fc2T + col * 256;
            v4f acc0 = {0.f, 0.f, 0.f, 0.f}, acc1 = {0.f, 0.f, 0.f, 0.f};
            #pragma unroll
            for (int k0 = 0; k0 < 8; k0++) {
                v8s b = *(const v8s*)(bb + k0 * 32 + q * 8);
                acc0 = __builtin_amdgcn_mfma_f32_16x16x32_bf16(a0[k0], b, acc0, 0, 0, 0);
                acc1 = __builtin_amdgcn_mfma_f32_16x16x32_bf16(a1[k0], b, acc1, 0, 0, 0);
            }
            float bias = ldf(fc2_b, col, bf);
            #pragma unroll
            for (int r = 0; r < 4; r++) {
                sH[(q * 4 + r) * 520 + col]      = f2s(lrelu(acc0[r] + bias));
                sH[(16 + q * 4 + r) * 520 + col] = f2s(lrelu(acc1[r] + bias));
            }
        }
    }
    __syncthreads();

    {
        #pragma unroll
        for (int nt = 0; nt < 4; nt++) {
            int col = w * 64 + nt * 16 + ln;
            v4f acc0 = {0.f, 0.f, 0.f, 0.f}, acc1 = {0.f, 0.f, 0.f, 0.f};
            #pragma unroll
            for (int half = 0; half < 2; half++) {
                const short* bb = fc3T + col * 512 + half * 256;
                #pragma unroll
                for (int k0 = 0; k0 < 8; k0++) {
                    v8s b  = *(const v8s*)(bb + k0 * 32 + q * 8);
                    v8s a0 = *(const v8s*)&sH[ln * 520 + half * 256 + k0 * 32 + q * 8];
                    v8s a1 = *(const v8s*)&sH[(16 + ln) * 520 + half * 256 + k0 * 32 + q * 8];
                    acc0 = __builtin_amdgcn_mfma_f32_16x16x32_bf16(a0, b, acc0, 0, 0, 0);
                    acc1 = __builtin_amdgcn_mfma_f32_16x16x32_bf16(a1, b, acc1, 0, 0, 0);
                }
            }
            float bias = ldf(fc3_b, col, bf);
            #pragma unroll
            for (int r = 0; r < 4; r++) {
                s3[(q * 4 + r) * 264 + col]      = f2s(lrelu(acc0[r] + bias));
                s3[(16 + q * 4 + r) * 264 + col] = f2s(lrelu(acc1[r] + bias));
            }
        }
    }
    __syncthreads();

    {
        int vi = t >> 3, l = t & 7;
        float p0 = 0.f, p1 = 0.f, p2 = 0.f;
        for (int k = l; k < 256; k += 8) {
            float a = s2f(s3[vi * 264 + k]);
            p0 += a * s2f(sW4[0 * 256 + k]);
            p1 += a * s2f(sW4[1 * 256 + k]);
            p2 += a * s2f(sW4[2 * 256 + k]);
        }
        #pragma unroll
        for (int s = 4; s; s >>= 1) {
            p0 += __shfl_down(p0, s, 8);
            p1 += __shfl_down(p1, s, 8);
            p2 += __shfl_down(p2, s, 8);
        }
        if (l == 0) {
            int vert = base + vi;
            if (vert < NVERT) {
                float vx = ldf(v, vert * 3 + 0, bf);
                float vy = ldf(v, vert * 3 + 1, bf);
                float vz = ldf(v, vert * 3 + 2, bf);
                float o0 = vx + 0.1f * tanhf(p0 + ldf(fc4_b, 0, bf));
                float o1 = vy + 0.1f * tanhf(p1 + ldf(fc4_b, 1, bf));
                float o2 = vz + 0.1f * tanhf(p2 + ldf(fc4_b, 2, bf));
                if (bf) {
                    short* ob = (short*)out;
                    ob[vert * 3 + 0] = f2s(o0);
                    ob[vert * 3 + 1] = f2s(o1);
                    ob[vert * 3 + 2] = f2s(o2);
                } else {
                    float* of = (float*)out;
                    of[vert * 3 + 0] = o0;
                    of[vert * 3 + 1] = o1;
                    of[vert * 3 + 2] = o2;
                }
            }
        }
    }
}

extern "C" void kernel_launch(void* const* d_in, const int* in_sizes, int n_in,
                              void* d_out, int out_size, void* d_ws, size_t ws_size,
                              hipStream_t stream) {
    const void* v      = d_in[0];
    const int*  f      = (const int*)d_in[1];
    const void* volume = d_in[2];
    const void* fc1_w  = d_in[3];
    const void* fc1_b  = d_in[4];
    const void* fc2_w  = d_in[5];
    const void* fc2_b  = d_in[6];
    const void* fc3_w  = d_in[7];
    const void* fc3_b  = d_in[8];
    const void* fc4_w  = d_in[9];
    const void* fc4_b  = d_in[10];
    const void* conv_w = d_in[11];
    const void* conv_b = d_in[12];
    const void* lfc_w  = d_in[13];
    const void* lfc_b  = d_in[14];

    char* wsb = (char*)d_ws;
    const int big = (ws_size >= WS_BIG_NEED) ? 1 : 0;

    if (big) {
        int*   flag    = (int*)wsb;
        float* n_accum = (float*)(wsb + 64);
        float* vol1f   = (float*)(wsb + 1800064);
        float* vol2f   = (float*)(wsb + 5339008);
        short* Wcomb   = (short*)(wsb + 5781376);
        float* bcomb   = (float*)(wsb + 5879680);
        short* fc2T    = (short*)(wsb + 5880192);
        short* fc3T    = (short*)(wsb + 6142336);
        short* xloc    = (short*)(wsb + 6404480);

        hipMemsetAsync(n_accum, 0, NVERT * 3 * sizeof(float), stream);
        detect_kernel<<<1, 256, 0, stream>>>(v, flag);
        mega_prep_kernel<<<NB_MEGA, 256, 0, stream>>>(
            v, f, n_accum, volume,
            (short*)wsb, vol1f, (short*)wsb, vol2f,
            fc2_w, fc3_w, fc2T, fc3T,
            conv_w, lfc_w, conv_b, lfc_b, Wcomb, bcomb, flag, 1);
        gather_conv_kernel<<<(NVERT + TVB - 1) / TVB, 256, 0, stream>>>(
            v, volume, vol1f, vol2f, Wcomb, bcomb, xloc, flag);
        mlp_kernel<<<(NVERT + MTV - 1) / MTV, 256, 0, stream>>>(
            v, n_accum, xloc, fc2T, fc3T,
            fc1_w, fc1_b, fc2_b, fc3_b, fc4_w, fc4_b, d_out, flag);
    } else {
        int*   flag    = (int*)wsb;
        float* n_accum = (float*)(wsb + 64);
        short* vol1    = (short*)(wsb + 1800064);
        short* vol2    = (short*)(wsb + 3569536);
        short* Wcomb   = (short*)(wsb + 3790720);
        float* bcomb   = (float*)(wsb + 3889024);
        short* fc2T    = (short*)(wsb + 3889536);
        short* fc3T    = (short*)(wsb + 4151680);

        hipMemsetAsync(n_accum, 0, NVERT * 3 * sizeof(float), stream);
        detect_kernel<<<1, 256, 0, stream>>>(v, flag);
        mega_prep_kernel<<<NB_MEGA, 256, 0, stream>>>(
            v, f, n_accum, volume,
            vol1, (float*)wsb, vol2, (float*)wsb,
            fc2_w, fc3_w, fc2T, fc3T,
            conv_w, lfc_w, conv_b, lfc_b, Wcomb, bcomb, flag, 0);
        fused_mfma_kernel<<<(NVERT + TVB - 1) / TVB, 256, 0, stream>>>(
            v, n_accum, volume, vol1, vol2, Wcomb, bcomb, fc2T, fc3T,
            fc1_w, fc1_b, fc2_b, fc3_b, fc4_w, fc4_b, d_out, flag);
    }
}